// Round 1
// baseline (267.751 us; speedup 1.0000x reference)
//
#include <hip/hip_runtime.h>

#define B_SZ 4
#define T 512
#define H 256
#define N 64
#define LC 96       // conv truncation: ||A||=1/1.1 -> tail < ~1e-4
#define TT 8        // t-rows per block
#define EPSLN 1e-5f

__device__ __forceinline__ float wave_reduce_sum(float v) {
#pragma unroll
    for (int m = 1; m < 64; m <<= 1) v += __shfl_xor(v, m, 64);
    return v;
}

__device__ __forceinline__ float lane_bcast(float v, int lane) {
    return __int_as_float(__builtin_amdgcn_readlane(__float_as_int(v), lane));
}

// Front kernel: block 0 = W-prep (w_j = Cbar^T A^j chain, wave per layer);
// blocks 1..256 = input GEMM (h0 = x@Win^T + bin) + B-proj for layer 0.
__global__ void __launch_bounds__(256) k_front(
    const float* __restrict__ x, const float* __restrict__ Win,
    const float* __restrict__ bin, const float* __restrict__ Bm,
    const float* __restrict__ Cm, const float* __restrict__ A,
    float* __restrict__ hout, float* __restrict__ binp, float* __restrict__ wbuf)
{
    __shared__ float red[4][TT][N];
    __shared__ __align__(16) float yl[TT][H];

    const int bid = blockIdx.x;
    const int tid = threadIdx.x;

    if (bid == 0) {
        // ---- W-prep: wave l handles layer l ----
        const int l = tid >> 6, lane = tid & 63;
        // Cbar[lane] = mean_h Cm[l][h][lane]
        float c0 = 0.f, c1 = 0.f, c2 = 0.f, c3 = 0.f;
        const float* cp = Cm + l * H * N + lane;
#pragma unroll 4
        for (int h = 0; h < H; h += 4) {
            c0 += cp[(h + 0) * N]; c1 += cp[(h + 1) * N];
            c2 += cp[(h + 2) * N]; c3 += cp[(h + 3) * N];
        }
        float w = ((c0 + c1) + (c2 + c3)) * (1.0f / H);
        // A column 'lane' into registers: areg[n] = A[l][n][lane]
        float areg[N];
        const float* ap = A + l * N * N + lane;
#pragma unroll
        for (int nn = 0; nn < N; ++nn) areg[nn] = ap[nn * N];

        wbuf[(l * LC + 0) * N + lane] = w;
        for (int j = 1; j < LC; ++j) {
            float p0 = 0.f, p1 = 0.f, p2 = 0.f, p3 = 0.f;
#pragma unroll
            for (int nn = 0; nn < N; nn += 4) {
                p0 += lane_bcast(w, nn + 0) * areg[nn + 0];
                p1 += lane_bcast(w, nn + 1) * areg[nn + 1];
                p2 += lane_bcast(w, nn + 2) * areg[nn + 2];
                p3 += lane_bcast(w, nn + 3) * areg[nn + 3];
            }
            w = (p0 + p1) + (p2 + p3);
            wbuf[(l * LC + j) * N + lane] = w;
        }
        return;
    }

    // ---- role A: input GEMM + B-proj(layer 0) ----
    const int rb = bid - 1;
    const int b = rb >> 6, tt = rb & 63;
    const int t0 = tt * TT;
    const int h = tid;

    const float* xbase = x + (size_t)(b * T + t0) * H;
    float y[TT];
#pragma unroll
    for (int r = 0; r < TT; ++r) y[r] = bin[h];

    const float4* wrow = (const float4*)(Win + (size_t)h * H);
    for (int k0 = 0; k0 < H / 4; ++k0) {
        float4 wv = wrow[k0];
#pragma unroll
        for (int r = 0; r < TT; ++r) {
            float4 xv = ((const float4*)(xbase + r * H))[k0];  // wave-uniform
            y[r] += wv.x * xv.x + wv.y * xv.y + wv.z * xv.z + wv.w * xv.w;
        }
    }
#pragma unroll
    for (int r = 0; r < TT; ++r) {
        hout[(size_t)(b * T + t0 + r) * H + h] = y[r];
        yl[r][h] = y[r];
    }
    __syncthreads();

    // B-proj: Binp[b,t,n] = sum_h Bm[0][n][h] * h0[b,t,h]
    {
        const int n = tid & 63, g = tid >> 6;
        const float4* brow = (const float4*)(Bm + (size_t)n * H);
#pragma unroll
        for (int r = 0; r < TT; ++r) {
            float p = 0.f;
#pragma unroll 4
            for (int k4 = g * 16; k4 < g * 16 + 16; ++k4) {
                float4 bv = brow[k4];
                float4 zv = *(const float4*)(&yl[r][k4 * 4]);
                p += bv.x * zv.x + bv.y * zv.y + bv.z * zv.z + bv.w * zv.w;
            }
            red[g][r][n] = p;
        }
    }
    __syncthreads();
    for (int idx = tid; idx < TT * N; idx += 256) {
        int r = idx >> 6, nn = idx & 63;
        float s = red[0][r][nn] + red[1][r][nn] + red[2][r][nn] + red[3][r][nn];
        binp[(size_t)(b * T + t0 + idx >> 6, 0) * 0 + (size_t)(b * T + t0 + r) * N + nn] = s;
    }
}

// Per-layer kernel: conv(c) + D-GEMM + gelu + residual + LN (+ Bproj-next | + LN2 + outGEMM)
template <bool LAST>
__global__ void __launch_bounds__(256) k_layer(
    const int l,
    const float* __restrict__ hin, const float* __restrict__ binp_in,
    const float* __restrict__ wbuf, const float* __restrict__ Dm,
    const float* __restrict__ Bnext,
    const float* __restrict__ Wout, const float* __restrict__ bout,
    float* __restrict__ hout, float* __restrict__ binp_out,
    float* __restrict__ zscratch, float* __restrict__ out)
{
    __shared__ float red[4][TT][N];
    __shared__ __align__(16) float yl[TT][H];
    __shared__ float cfin[TT];
    __shared__ float stats[TT][2];

    const int bid = blockIdx.x, tid = threadIdx.x;
    const int b = bid >> 6, tt = bid & 63, t0 = tt * TT;
    const int lane = tid & 63, wv = tid >> 6;

    // ---- Phase 1: conv partials: c[t] = sum_j w_j . Binp[t-1-j] ----
    {
        float cacc[TT];
#pragma unroll
        for (int r = 0; r < TT; ++r) cacc[r] = 0.f;
        const float* wl = wbuf + (size_t)l * LC * N + lane;
        const float* bp = binp_in + (size_t)b * T * N + lane;
        for (int jj = wv; jj < LC; jj += 4) {
            float wj = wl[(size_t)jj * N];
            int tb = t0 - 1 - jj;
#pragma unroll
            for (int r = 0; r < TT; ++r) {
                int trow = tb + r;
                if (trow >= 0) cacc[r] += wj * bp[(size_t)trow * N];
            }
        }
#pragma unroll
        for (int r = 0; r < TT; ++r) red[wv][r][lane] = cacc[r];
    }
    __syncthreads();
#pragma unroll
    for (int rr = 0; rr < 2; ++rr) {
        int r = wv + rr * 4;
        float v = red[0][r][lane] + red[1][r][lane] + red[2][r][lane] + red[3][r][lane];
        v = wave_reduce_sum(v);
        if (lane == 0) cfin[r] = v;
    }
    __syncthreads();

    // ---- Phase 2: y[t,h] = c[t] + sum_k D[h,k] hin[t,k]; gelu + residual ----
    const int h = tid;
    float y[TT];
    const float* hbase = hin + (size_t)(b * T + t0) * H;
    {
#pragma unroll
        for (int r = 0; r < TT; ++r) y[r] = cfin[r];
        const float4* drow = (const float4*)(Dm + ((size_t)l * H + h) * H);
        for (int k0 = 0; k0 < H / 4; ++k0) {
            float4 dv = drow[k0];
#pragma unroll
            for (int r = 0; r < TT; ++r) {
                float4 xv = ((const float4*)(hbase + r * H))[k0];  // wave-uniform
                y[r] += dv.x * xv.x + dv.y * xv.y + dv.z * xv.z + dv.w * xv.w;
            }
        }
#pragma unroll
        for (int r = 0; r < TT; ++r) {
            float v = y[r];
            float ge = 0.5f * v * (1.0f + erff(v * 0.70710678118654752f));
            y[r] = ge + hbase[(size_t)r * H + h];
            yl[r][h] = y[r];
        }
    }
    __syncthreads();

    // ---- Phase 3: LayerNorm ----
#pragma unroll
    for (int rr = 0; rr < 2; ++rr) {
        int r = wv + rr * 4;
        float s = 0.f, sq = 0.f;
#pragma unroll
        for (int q = 0; q < 4; ++q) { float v = yl[r][lane + 64 * q]; s += v; sq += v * v; }
        s = wave_reduce_sum(s); sq = wave_reduce_sum(sq);
        if (lane == 0) {
            float m = s * (1.0f / H);
            float var = sq * (1.0f / H) - m * m;
            stats[r][0] = m; stats[r][1] = 1.0f / sqrtf(var + EPSLN);
        }
    }
    __syncthreads();
#pragma unroll
    for (int r = 0; r < TT; ++r) y[r] = (y[r] - stats[r][0]) * stats[r][1];

    if constexpr (!LAST) {
#pragma unroll
        for (int r = 0; r < TT; ++r) {
            hout[(size_t)(b * T + t0 + r) * H + h] = y[r];
            yl[r][h] = y[r];
        }
        __syncthreads();
        // B-proj for next layer
        {
            const int n = lane, g = wv;
            const float4* brow = (const float4*)(Bnext + (size_t)n * H);
#pragma unroll
            for (int r = 0; r < TT; ++r) {
                float p = 0.f;
#pragma unroll 4
                for (int k4 = g * 16; k4 < g * 16 + 16; ++k4) {
                    float4 bv = brow[k4];
                    float4 zv = *(const float4*)(&yl[r][k4 * 4]);
                    p += bv.x * zv.x + bv.y * zv.y + bv.z * zv.z + bv.w * zv.w;
                }
                red[g][r][n] = p;
            }
        }
        __syncthreads();
        for (int idx = tid; idx < TT * N; idx += 256) {
            int r = idx >> 6, nn = idx & 63;
            float s = red[0][r][nn] + red[1][r][nn] + red[2][r][nn] + red[3][r][nn];
            binp_out[(size_t)(b * T + t0 + r) * N + nn] = s;
        }
    } else {
        // ---- second LN then out-GEMM ----
#pragma unroll
        for (int r = 0; r < TT; ++r) yl[r][h] = y[r];
        __syncthreads();
#pragma unroll
        for (int rr = 0; rr < 2; ++rr) {
            int r = wv + rr * 4;
            float s = 0.f, sq = 0.f;
#pragma unroll
            for (int q = 0; q < 4; ++q) { float v = yl[r][lane + 64 * q]; s += v; sq += v * v; }
            s = wave_reduce_sum(s); sq = wave_reduce_sum(sq);
            if (lane == 0) {
                float m = s * (1.0f / H);
                float var = sq * (1.0f / H) - m * m;
                stats[r][0] = m; stats[r][1] = 1.0f / sqrtf(var + EPSLN);
            }
        }
        __syncthreads();
#pragma unroll
        for (int r = 0; r < TT; ++r) {
            float z2 = (y[r] - stats[r][0]) * stats[r][1];
            zscratch[(size_t)(b * T + t0 + r) * H + h] = z2;
        }
        __syncthreads();
        // out = z2 @ Wout^T + bout ; z2 rows read wave-uniform (own writes, post-barrier)
        float acc[TT];
#pragma unroll
        for (int r = 0; r < TT; ++r) acc[r] = bout[h];
        const float4* wrow = (const float4*)(Wout + (size_t)h * H);
        const float* zbase = zscratch + (size_t)(b * T + t0) * H;
        for (int k0 = 0; k0 < H / 4; ++k0) {
            float4 wv4 = wrow[k0];
#pragma unroll
            for (int r = 0; r < TT; ++r) {
                float4 zv = ((const float4*)(zbase + r * H))[k0];
                acc[r] += wv4.x * zv.x + wv4.y * zv.y + wv4.z * zv.z + wv4.w * zv.w;
            }
        }
#pragma unroll
        for (int r = 0; r < TT; ++r)
            out[(size_t)(b * T + t0 + r) * H + h] = acc[r];
    }
}

extern "C" void kernel_launch(void* const* d_in, const int* in_sizes, int n_in,
                              void* d_out, int out_size, void* d_ws, size_t ws_size,
                              hipStream_t stream) {
    (void)in_sizes; (void)n_in; (void)out_size; (void)ws_size;
    const float* x    = (const float*)d_in[0];
    const float* Win  = (const float*)d_in[1];
    const float* bin  = (const float*)d_in[2];
    const float* Wout = (const float*)d_in[3];
    const float* bout = (const float*)d_in[4];
    const float* A    = (const float*)d_in[5];
    const float* Bm   = (const float*)d_in[6];
    const float* Cm   = (const float*)d_in[7];
    const float* Dm   = (const float*)d_in[8];

    float* ws   = (float*)d_ws;
    float* Wbuf = ws;                          // 4*96*64     = 24576
    float* hA   = Wbuf + 4 * LC * N;           // 4*512*256   = 524288
    float* hB   = hA + (size_t)B_SZ * T * H;
    float* BiA  = hB + (size_t)B_SZ * T * H;   // 4*512*64    = 131072
    float* BiB  = BiA + (size_t)B_SZ * T * N;
    float* outp = (float*)d_out;

    const int NB = B_SZ * (T / TT);            // 256 row-blocks

    k_front<<<dim3(NB + 1), dim3(256), 0, stream>>>(x, Win, bin, Bm, Cm, A, hA, BiA, Wbuf);
    k_layer<false><<<dim3(NB), dim3(256), 0, stream>>>(0, hA, BiA, Wbuf, Dm, Bm + 1 * N * H,
                                                       nullptr, nullptr, hB, BiB, nullptr, nullptr);
    k_layer<false><<<dim3(NB), dim3(256), 0, stream>>>(1, hB, BiB, Wbuf, Dm, Bm + 2 * N * H,
                                                       nullptr, nullptr, hA, BiA, nullptr, nullptr);
    k_layer<false><<<dim3(NB), dim3(256), 0, stream>>>(2, hA, BiA, Wbuf, Dm, Bm + 3 * N * H,
                                                       nullptr, nullptr, hB, BiB, nullptr, nullptr);
    k_layer<true ><<<dim3(NB), dim3(256), 0, stream>>>(3, hB, BiB, Wbuf, Dm, nullptr,
                                                       Wout, bout, nullptr, nullptr, hA, outp);
}

// Round 2
// 153.520 us; speedup vs baseline: 1.7441x; 1.7441x over previous
//
#include <hip/hip_runtime.h>

#define TSEQ 512
#define HDIM 256
#define NDIM 64
#define LC   64        // conv truncation; ||A||=1/1.1 -> tail ~0.9^64 ≈ 2e-3 rel
#define MT   16        // rows (t) per block = MFMA M
#define YSTR 260       // padded f32 LDS row stride (260%32=4 -> stagger banks)

typedef __attribute__((ext_vector_type(4))) float  f32x4;
typedef __attribute__((ext_vector_type(8))) short  s16x8;
typedef __attribute__((ext_vector_type(4))) unsigned short u16x4;

__device__ __forceinline__ float wave_red(float v) {
#pragma unroll
    for (int m = 1; m < 64; m <<= 1) v += __shfl_xor(v, m, 64);
    return v;
}
__device__ __forceinline__ float lane_bcast(float v, int lane) {
    return __int_as_float(__builtin_amdgcn_readlane(__float_as_int(v), lane));
}
__device__ __forceinline__ unsigned short f2bf(float f) {
    unsigned u = __float_as_uint(f);
    u += 0x7fffu + ((u >> 16) & 1u);
    return (unsigned short)(u >> 16);
}
__device__ __forceinline__ float bf2f(unsigned short h) {
    return __uint_as_float(((unsigned)h) << 16);
}
// byte offset of 16B chunk `chunk` in row `row` of a [16][256] bf16 LDS tile,
// XOR-swizzled so A-frag column reads (16 rows, same chunk) spread over 8 bank-groups
__device__ __forceinline__ int swz(int row, int chunk) {
    return row * 512 + (((chunk) ^ (row & 7)) << 4);
}

// ---------------- prep: f32 -> bf16 conversions ----------------
__global__ void __launch_bounds__(256) k_prep(
    const float* __restrict__ x, const float* __restrict__ Win,
    const float* __restrict__ Wout, const float* __restrict__ Bm,
    const float* __restrict__ Dm,
    unsigned short* __restrict__ x_bf, unsigned short* __restrict__ Win_bf,
    unsigned short* __restrict__ Wout_bf, unsigned short* __restrict__ Bm_bf,
    unsigned short* __restrict__ Dm_bf)
{
    const int bid = blockIdx.x, tid = threadIdx.x;
    const float* src; unsigned short* dst; size_t base;
    if      (bid < 128) { src = x;    dst = x_bf;    base = (size_t)bid * 4096; }
    else if (bid < 144) { src = Win;  dst = Win_bf;  base = (size_t)(bid - 128) * 4096; }
    else if (bid < 160) { src = Wout; dst = Wout_bf; base = (size_t)(bid - 144) * 4096; }
    else if (bid < 176) { src = Bm;   dst = Bm_bf;   base = (size_t)(bid - 160) * 4096; }
    else                { src = Dm;   dst = Dm_bf;   base = (size_t)(bid - 176) * 4096; }
    const size_t i0 = base + (size_t)tid * 16;
#pragma unroll
    for (int i = 0; i < 4; ++i) {
        f32x4 v = *(const f32x4*)(src + i0 + i * 4);
        u16x4 p; p[0] = f2bf(v[0]); p[1] = f2bf(v[1]); p[2] = f2bf(v[2]); p[3] = f2bf(v[3]);
        *(u16x4*)(dst + i0 + i * 4) = p;
    }
}

// ---------------- front: in-GEMM + Bproj0 (blocks 0..127), W-chain (block 128) ----
__global__ void __launch_bounds__(256) k_front(
    const unsigned short* __restrict__ x_bf, const unsigned short* __restrict__ Win_bf,
    const float* __restrict__ bin, const unsigned short* __restrict__ B0_bf,
    const float* __restrict__ Cm, const float* __restrict__ A,
    unsigned short* __restrict__ h0_bf, float* __restrict__ binp0,
    float* __restrict__ wbuf)
{
    __shared__ __align__(16) unsigned short xl[MT * HDIM];
    __shared__ __align__(16) float yl[MT * YSTR];

    const int bid = blockIdx.x, tid = threadIdx.x;
    const int lane = tid & 63, wv = tid >> 6;

    if (bid == 128) {   // ---- w_j = Cbar^T A^j chain, wave per layer ----
        const int l = wv;
        const float* cp = Cm + (size_t)l * HDIM * NDIM + lane;
        float c0 = 0.f, c1 = 0.f, c2 = 0.f, c3 = 0.f;
        for (int h = 0; h < HDIM; h += 4) {
            c0 += cp[(h + 0) * NDIM]; c1 += cp[(h + 1) * NDIM];
            c2 += cp[(h + 2) * NDIM]; c3 += cp[(h + 3) * NDIM];
        }
        float w = ((c0 + c1) + (c2 + c3)) * (1.0f / HDIM);
        float areg[NDIM];
        const float* ap = A + (size_t)l * NDIM * NDIM + lane;
#pragma unroll
        for (int n = 0; n < NDIM; ++n) areg[n] = ap[n * NDIM];
        float* wl = wbuf + (size_t)l * LC * NDIM;
        wl[lane] = w;
        for (int j = 1; j < LC; ++j) {
            float p0 = 0.f, p1 = 0.f, p2 = 0.f, p3 = 0.f;
#pragma unroll
            for (int n = 0; n < NDIM; n += 4) {
                p0 += lane_bcast(w, n + 0) * areg[n + 0];
                p1 += lane_bcast(w, n + 1) * areg[n + 1];
                p2 += lane_bcast(w, n + 2) * areg[n + 2];
                p3 += lane_bcast(w, n + 3) * areg[n + 3];
            }
            w = (p0 + p1) + (p2 + p3);
            wl[j * NDIM + lane] = w;
        }
        return;
    }

    const int b = bid >> 5, tb = bid & 31, t0 = tb * MT;
    const size_t grow = (size_t)(b * TSEQ + t0);
    const int m = lane & 15, cg = lane >> 4;
    const f32x4 z4 = {0.f, 0.f, 0.f, 0.f};

    { // stage x rows -> swizzled LDS
        const unsigned short* gs = x_bf + grow * HDIM;
        for (int ci = tid; ci < MT * 32; ci += 256) {
            int row = ci >> 5, c = ci & 31;
            s16x8 v = *(const s16x8*)(gs + (size_t)row * HDIM + c * 8);
            *(s16x8*)((char*)xl + swz(row, c)) = v;
        }
    }
    __syncthreads();

    // GEMM: h0 = x @ Win^T
    f32x4 acc[4]; acc[0] = z4; acc[1] = z4; acc[2] = z4; acc[3] = z4;
    for (int ks = 0; ks < 8; ++ks) {
        s16x8 av = *(const s16x8*)((const char*)xl + swz(m, ks * 4 + cg));
#pragma unroll
        for (int nt = 0; nt < 4; ++nt) {
            int n = wv * 64 + nt * 16 + m;
            s16x8 bv = *(const s16x8*)(Win_bf + (size_t)n * HDIM + ks * 32 + cg * 8);
            acc[nt] = __builtin_amdgcn_mfma_f32_16x16x32_bf16(av, bv, acc[nt], 0, 0, 0);
        }
    }
#pragma unroll
    for (int nt = 0; nt < 4; ++nt) {
        int hcol = wv * 64 + nt * 16 + m;
        float bi = bin[hcol];
#pragma unroll
        for (int reg = 0; reg < 4; ++reg) {
            int trow = cg * 4 + reg;
            yl[trow * YSTR + hcol] = acc[nt][reg] + bi;
        }
    }
    __syncthreads();

    // pack rows -> global h0_bf + LDS z (for B-proj)
#pragma unroll
    for (int q = 0; q < 4; ++q) {
        int r = wv * 4 + q;
        f32x4 yv = *(const f32x4*)(yl + r * YSTR + lane * 4);
        u16x4 zp; zp[0] = f2bf(yv[0]); zp[1] = f2bf(yv[1]); zp[2] = f2bf(yv[2]); zp[3] = f2bf(yv[3]);
        *(u16x4*)(h0_bf + (grow + r) * HDIM + lane * 4) = zp;
        *(u16x4*)((char*)xl + swz(r, lane >> 1) + (lane & 1) * 8) = zp;
    }
    __syncthreads();

    // B-proj layer 0: Binp0 = h0 @ B0^T   (N_out = 64, one 16-tile per wave)
    {
        f32x4 accb = z4;
        const int n0 = wv * 16;
        for (int ks = 0; ks < 8; ++ks) {
            s16x8 av = *(const s16x8*)((const char*)xl + swz(m, ks * 4 + cg));
            s16x8 bv = *(const s16x8*)(B0_bf + (size_t)(n0 + m) * HDIM + ks * 32 + cg * 8);
            accb = __builtin_amdgcn_mfma_f32_16x16x32_bf16(av, bv, accb, 0, 0, 0);
        }
#pragma unroll
        for (int reg = 0; reg < 4; ++reg) {
            int trow = cg * 4 + reg;
            binp0[((size_t)b * TSEQ + t0 + trow) * NDIM + n0 + m] = accb[reg];
        }
    }
}

// ---------------- per-layer: conv + D-GEMM + gelu + residual + LN (+ Bproj | + LN2 + outGEMM) ----
template <bool LAST>
__global__ void __launch_bounds__(256) k_layer(
    const unsigned short* __restrict__ hin_bf, const float* __restrict__ binp_in,
    const float* __restrict__ wl_, const unsigned short* __restrict__ D_bf,
    const unsigned short* __restrict__ Bn_bf, const unsigned short* __restrict__ Wo_bf,
    unsigned short* __restrict__ hout_bf, float* __restrict__ binp_out,
    const float* __restrict__ bout, float* __restrict__ out)
{
    __shared__ __align__(16) unsigned short xl[MT * HDIM];
    __shared__ __align__(16) float yl[MT * YSTR];
    __shared__ float cfin[MT];

    const int bid = blockIdx.x, tid = threadIdx.x;
    const int lane = tid & 63, wv = tid >> 6;
    const int b = bid >> 5, tb = bid & 31, t0 = tb * MT;
    const size_t grow = (size_t)(b * TSEQ + t0);
    const int m = lane & 15, cg = lane >> 4;
    const f32x4 z4 = {0.f, 0.f, 0.f, 0.f};

    { // stage hin rows -> swizzled LDS
        const unsigned short* gs = hin_bf + grow * HDIM;
        for (int ci = tid; ci < MT * 32; ci += 256) {
            int row = ci >> 5, c = ci & 31;
            s16x8 v = *(const s16x8*)(gs + (size_t)row * HDIM + c * 8);
            *(s16x8*)((char*)xl + swz(row, c)) = v;
        }
    }

    // ---- conv: c[t] = sum_j w_j . Binp[t-1-j]; wave handles 4 rows, rolling window ----
    {
        const int r0 = wv * 4;
        const float* bp = binp_in + (size_t)b * TSEQ * NDIM;
        float cacc0 = 0.f, cacc1 = 0.f, cacc2 = 0.f, cacc3 = 0.f;
        const int base = t0 + r0 - 1;            // row for (q=0, j=0)
        float v0 = (base >= 0) ? bp[(size_t)base * NDIM + lane] : 0.f;
        float v1 = bp[(size_t)(base + 1) * NDIM + lane];
        float v2 = bp[(size_t)(base + 2) * NDIM + lane];
        float v3 = bp[(size_t)(base + 3) * NDIM + lane];
        const int jmax = min(LC - 1, t0 + r0 + 2);
        for (int j = 0; j <= jmax; ++j) {
            float wj = wl_[j * NDIM + lane];
            cacc0 += wj * v0; cacc1 += wj * v1; cacc2 += wj * v2; cacc3 += wj * v3;
            v3 = v2; v2 = v1; v1 = v0;
            int nr = base - 1 - j;
            v0 = (nr >= 0) ? bp[(size_t)nr * NDIM + lane] : 0.f;
        }
        float s0 = wave_red(cacc0); float s1 = wave_red(cacc1);
        float s2 = wave_red(cacc2); float s3 = wave_red(cacc3);
        if (lane == 0) { cfin[r0] = s0; cfin[r0 + 1] = s1; cfin[r0 + 2] = s2; cfin[r0 + 3] = s3; }
    }
    __syncthreads();

    // ---- D-GEMM + finalize (c + gelu + residual) -> yl ----
    f32x4 acc[4]; acc[0] = z4; acc[1] = z4; acc[2] = z4; acc[3] = z4;
    for (int ks = 0; ks < 8; ++ks) {
        s16x8 av = *(const s16x8*)((const char*)xl + swz(m, ks * 4 + cg));
#pragma unroll
        for (int nt = 0; nt < 4; ++nt) {
            int n = wv * 64 + nt * 16 + m;
            s16x8 bv = *(const s16x8*)(D_bf + (size_t)n * HDIM + ks * 32 + cg * 8);
            acc[nt] = __builtin_amdgcn_mfma_f32_16x16x32_bf16(av, bv, acc[nt], 0, 0, 0);
        }
    }
#pragma unroll
    for (int nt = 0; nt < 4; ++nt) {
        int hcol = wv * 64 + nt * 16 + m;
#pragma unroll
        for (int reg = 0; reg < 4; ++reg) {
            int trow = cg * 4 + reg;
            float val = acc[nt][reg] + cfin[trow];
            float g = 0.5f * val * (1.0f + erff(val * 0.70710678118654752f));
            int byteo = swz(trow, hcol >> 3) + (hcol & 7) * 2;
            float r = bf2f(*(const unsigned short*)((const char*)xl + byteo));
            yl[trow * YSTR + hcol] = g + r;
        }
    }
    __syncthreads();

    // ---- LayerNorm (and LN2 fused analytically for LAST) -> z into xl (+hout) ----
#pragma unroll
    for (int q = 0; q < 4; ++q) {
        int r = wv * 4 + q;
        f32x4 yv = *(const f32x4*)(yl + r * YSTR + lane * 4);
        float s = (yv[0] + yv[1]) + (yv[2] + yv[3]);
        float sq = yv[0] * yv[0] + yv[1] * yv[1] + yv[2] * yv[2] + yv[3] * yv[3];
        s = wave_red(s); sq = wave_red(sq);
        float mn = s * (1.0f / HDIM);
        float var = sq * (1.0f / HDIM) - mn * mn;
        float rs = rsqrtf(var + 1e-5f);
        if (LAST) {                       // LN2(LN(y)): mean=0 exactly, var_z = var/(var+eps)
            float vz = var * rs * rs;
            rs = rs * rsqrtf(vz + 1e-5f);
        }
        f32x4 zv; zv[0] = (yv[0] - mn) * rs; zv[1] = (yv[1] - mn) * rs;
        zv[2] = (yv[2] - mn) * rs; zv[3] = (yv[3] - mn) * rs;
        u16x4 zp; zp[0] = f2bf(zv[0]); zp[1] = f2bf(zv[1]); zp[2] = f2bf(zv[2]); zp[3] = f2bf(zv[3]);
        if constexpr (!LAST)
            *(u16x4*)(hout_bf + (grow + r) * HDIM + lane * 4) = zp;
        *(u16x4*)((char*)xl + swz(r, lane >> 1) + (lane & 1) * 8) = zp;
    }
    __syncthreads();

    if constexpr (!LAST) {
        // ---- B-proj next layer ----
        f32x4 accb = z4;
        const int n0 = wv * 16;
        for (int ks = 0; ks < 8; ++ks) {
            s16x8 av = *(const s16x8*)((const char*)xl + swz(m, ks * 4 + cg));
            s16x8 bv = *(const s16x8*)(Bn_bf + (size_t)(n0 + m) * HDIM + ks * 32 + cg * 8);
            accb = __builtin_amdgcn_mfma_f32_16x16x32_bf16(av, bv, accb, 0, 0, 0);
        }
#pragma unroll
        for (int reg = 0; reg < 4; ++reg) {
            int trow = cg * 4 + reg;
            binp_out[((size_t)b * TSEQ + t0 + trow) * NDIM + n0 + m] = accb[reg];
        }
    } else {
        // ---- out-GEMM: out = z2 @ Wout^T + bout ----
        f32x4 acc2[4]; acc2[0] = z4; acc2[1] = z4; acc2[2] = z4; acc2[3] = z4;
        for (int ks = 0; ks < 8; ++ks) {
            s16x8 av = *(const s16x8*)((const char*)xl + swz(m, ks * 4 + cg));
#pragma unroll
            for (int nt = 0; nt < 4; ++nt) {
                int n = wv * 64 + nt * 16 + m;
                s16x8 bv = *(const s16x8*)(Wo_bf + (size_t)n * HDIM + ks * 32 + cg * 8);
                acc2[nt] = __builtin_amdgcn_mfma_f32_16x16x32_bf16(av, bv, acc2[nt], 0, 0, 0);
            }
        }
#pragma unroll
        for (int nt = 0; nt < 4; ++nt) {
            int hcol = wv * 64 + nt * 16 + m;
            float bo = bout[hcol];
#pragma unroll
            for (int reg = 0; reg < 4; ++reg) {
                int trow = cg * 4 + reg;
                out[(grow + trow) * HDIM + hcol] = acc2[nt][reg] + bo;
            }
        }
    }
}

extern "C" void kernel_launch(void* const* d_in, const int* in_sizes, int n_in,
                              void* d_out, int out_size, void* d_ws, size_t ws_size,
                              hipStream_t stream) {
    (void)in_sizes; (void)n_in; (void)out_size; (void)ws_size;
    const float* x    = (const float*)d_in[0];
    const float* Win  = (const float*)d_in[1];
    const float* bin  = (const float*)d_in[2];
    const float* Wout = (const float*)d_in[3];
    const float* bout = (const float*)d_in[4];
    const float* A    = (const float*)d_in[5];
    const float* Bm   = (const float*)d_in[6];
    const float* Cm   = (const float*)d_in[7];
    const float* Dm   = (const float*)d_in[8];

    float* ws = (float*)d_ws;
    float* wbuf = ws;                                           // 4*64*64 f32 = 16384
    unsigned short* x_bf    = (unsigned short*)(ws + 16384);    // 524288 bf16
    unsigned short* Win_bf  = x_bf + 524288;                    // 65536
    unsigned short* Wout_bf = Win_bf + 65536;                   // 65536
    unsigned short* Bm_bf   = Wout_bf + 65536;                  // 65536
    unsigned short* Dm_bf   = Bm_bf + 65536;                    // 262144
    unsigned short* hA_bf   = Dm_bf + 262144;                   // 524288
    unsigned short* hB_bf   = hA_bf + 524288;                   // 524288
    float* BiA = (float*)(hB_bf + 524288);                      // 131072 f32
    float* BiB = BiA + 131072;                                  // 131072 f32
    float* outp = (float*)d_out;

    k_prep<<<240, 256, 0, stream>>>(x, Win, Wout, Bm, Dm, x_bf, Win_bf, Wout_bf, Bm_bf, Dm_bf);
    k_front<<<129, 256, 0, stream>>>(x_bf, Win_bf, bin, Bm_bf, Cm, A, hA_bf, BiA, wbuf);
    k_layer<false><<<128, 256, 0, stream>>>(hA_bf, BiA, wbuf + 0 * LC * NDIM, Dm_bf + 0 * 65536,
                                            Bm_bf + 1 * 16384, nullptr, hB_bf, BiB, nullptr, nullptr);
    k_layer<false><<<128, 256, 0, stream>>>(hB_bf, BiB, wbuf + 1 * LC * NDIM, Dm_bf + 1 * 65536,
                                            Bm_bf + 2 * 16384, nullptr, hA_bf, BiA, nullptr, nullptr);
    k_layer<false><<<128, 256, 0, stream>>>(hA_bf, BiA, wbuf + 2 * LC * NDIM, Dm_bf + 2 * 65536,
                                            Bm_bf + 3 * 16384, nullptr, hB_bf, BiB, nullptr, nullptr);
    k_layer<true ><<<128, 256, 0, stream>>>(hB_bf, BiB, wbuf + 3 * LC * NDIM, Dm_bf + 3 * 65536,
                                            nullptr, Wout_bf, nullptr, nullptr, bout, outp);
}